// Round 1
// baseline (282.499 us; speedup 1.0000x reference)
//
#include <hip/hip_runtime.h>

#define NUM_CLASSES 5
#define BATCH 4
#define NPB (64 * 256 * 256)          // voxels per batch = 4,194,304
#define VEC_PER_BATCH (NPB / 4)       // int4 vectors per batch = 1,048,576
#define THREADS 256
#define VECS_PER_THREAD 16            // 64 voxels per thread
#define BLOCKS_PER_BATCH (VEC_PER_BATCH / (THREADS * VECS_PER_THREAD))  // 256

// Per-(batch,class) counters in d_ws: layout [b][slot], slot = c (pred), 5+c (target), 10+c (inter)
#define SLOTS 15

__global__ __launch_bounds__(THREADS) void dice_count_kernel(
    const int* __restrict__ pred, const int* __restrict__ targ,
    unsigned int* __restrict__ cnt) {
  const int b = blockIdx.y;
  const long long base = (long long)b * NPB;
  const int4* __restrict__ p4 = (const int4*)(pred + base);
  const int4* __restrict__ t4 = (const int4*)(targ + base);

  const int tid = blockIdx.x * THREADS + threadIdx.x;
  const int stride = BLOCKS_PER_BATCH * THREADS;  // 65536 vectors

  unsigned int pc[NUM_CLASSES] = {0, 0, 0, 0, 0};
  unsigned int tc[NUM_CLASSES] = {0, 0, 0, 0, 0};
  unsigned int ic[NUM_CLASSES] = {0, 0, 0, 0, 0};

#pragma unroll
  for (int k = 0; k < VECS_PER_THREAD; ++k) {
    const int4 pv = p4[tid + k * stride];
    const int4 tv = t4[tid + k * stride];
#pragma unroll
    for (int c = 0; c < NUM_CLASSES; ++c) {
      pc[c] += (unsigned)(pv.x == c) + (unsigned)(pv.y == c) +
               (unsigned)(pv.z == c) + (unsigned)(pv.w == c);
      tc[c] += (unsigned)(tv.x == c) + (unsigned)(tv.y == c) +
               (unsigned)(tv.z == c) + (unsigned)(tv.w == c);
      ic[c] += (unsigned)((pv.x == c) & (tv.x == c)) +
               (unsigned)((pv.y == c) & (tv.y == c)) +
               (unsigned)((pv.z == c) & (tv.z == c)) +
               (unsigned)((pv.w == c) & (tv.w == c));
    }
  }

  __shared__ unsigned int s[SLOTS];
  if (threadIdx.x < SLOTS) s[threadIdx.x] = 0;
  __syncthreads();
#pragma unroll
  for (int c = 0; c < NUM_CLASSES; ++c) {
    atomicAdd(&s[c], pc[c]);
    atomicAdd(&s[5 + c], tc[c]);
    atomicAdd(&s[10 + c], ic[c]);
  }
  __syncthreads();
  if (threadIdx.x < SLOTS)
    atomicAdd(&cnt[b * SLOTS + threadIdx.x], s[threadIdx.x]);
}

__global__ void dice_final_kernel(const unsigned int* __restrict__ cnt,
                                  float* __restrict__ out) {
  const int c = threadIdx.x;
  if (c < NUM_CLASSES) {
    float acc = 0.0f;
#pragma unroll
    for (int b = 0; b < BATCH; ++b) {
      const float ps = (float)cnt[b * SLOTS + c];
      const float ts = (float)cnt[b * SLOTS + 5 + c];
      const float is = (float)cnt[b * SLOTS + 10 + c];
      float num = 2.0f * is;
      float den = ps + ts;
      if (den == 0.0f) { num = 1.0f; den = 1.0f; }
      acc += num / den;
    }
    out[c] = acc * (1.0f / BATCH);
  }
}

extern "C" void kernel_launch(void* const* d_in, const int* in_sizes, int n_in,
                              void* d_out, int out_size, void* d_ws, size_t ws_size,
                              hipStream_t stream) {
  const int* pred = (const int*)d_in[0];
  const int* targ = (const int*)d_in[1];
  float* out = (float*)d_out;
  unsigned int* cnt = (unsigned int*)d_ws;

  hipMemsetAsync(cnt, 0, BATCH * SLOTS * sizeof(unsigned int), stream);

  dim3 grid(BLOCKS_PER_BATCH, BATCH);
  dice_count_kernel<<<grid, THREADS, 0, stream>>>(pred, targ, cnt);
  dice_final_kernel<<<1, 64, 0, stream>>>(cnt, out);
}